// Round 9
// baseline (362.656 us; speedup 1.0000x reference)
//
#include <hip/hip_runtime.h>
#include <hip/hip_bf16.h>
#include <math.h>

#define NN 50000
#define NE 800000
#define NB ((NN + 255) / 256)
#define NEG 0.2f
#define NHB ((NE + 255) / 256)

typedef __hip_bfloat16 bf16;
typedef __attribute__((ext_vector_type(8))) short s8v;
typedef __attribute__((ext_vector_type(4))) float f4v;

__device__ __forceinline__ float bf2f(unsigned short u) {
  union { unsigned int i; float f; } c;
  c.i = ((unsigned int)u) << 16;
  return c.f;
}
__device__ __forceinline__ float blo(unsigned int u) {
  union { unsigned int i; float f; } c;
  c.i = u << 16;
  return c.f;
}
__device__ __forceinline__ float bhi(unsigned int u) {
  union { unsigned int i; float f; } c;
  c.i = u & 0xffff0000u;
  return c.f;
}
__device__ __forceinline__ unsigned short f2b(float f) {
  bf16 b = __float2bfloat16(f);
  return __builtin_bit_cast(unsigned short, b);
}
__device__ __forceinline__ float lrelu(float t) { return (t > 0.f) ? t : NEG * t; }

// ---------------- prep: histogram + all fp32->bf16 conversions -------------
#define NX4 (NN * 32)           // x as float4 units
#define NW1 (256 * 128)
#define NW2 (64 * 256)
#define NPQ (128 * 64)
__global__ void prep_k(const int* __restrict__ ei, int* __restrict__ counts,
                       const float* __restrict__ x, const float* __restrict__ W1,
                       const float* __restrict__ W2, const float* __restrict__ mw1,
                       unsigned short* __restrict__ xb, unsigned short* __restrict__ w1t,
                       unsigned short* __restrict__ w2t, unsigned short* __restrict__ pqt) {
  int b = blockIdx.x;
  if (b < NHB) {
    int e = b * 256 + threadIdx.x;
    if (e < NE) atomicAdd(&counts[ei[NE + e]], 1);
    return;
  }
  int i = (b - NHB) * 256 + threadIdx.x;
  if (i < NX4) {
    float4 v = *(const float4*)(x + (size_t)i * 4);
    ushort4 o = {f2b(v.x), f2b(v.y), f2b(v.z), f2b(v.w)};
    *(ushort4*)(xb + (size_t)i * 4) = o;
    return;
  }
  i -= NX4;
  if (i < NW1) {  // w1t[n*128+k] = W1[k*256+n]
    int n = i >> 7, k = i & 127;
    w1t[i] = f2b(W1[(size_t)k * 256 + n]);
    return;
  }
  i -= NW1;
  if (i < NW2) {  // w2t[n*256+k] = W2[k*64+n]
    int n = i >> 8, k = i & 255;
    w2t[i] = f2b(W2[(size_t)k * 64 + n]);
    return;
  }
  i -= NW2;
  if (i < NPQ) {
    int n = i >> 6, k = i & 63;
    float v = (n < 64) ? mw1[(size_t)k * 64 + n] : mw1[(size_t)(64 + k) * 64 + (n - 64)];
    pqt[i] = f2b(v);
  }
}

// ---------------- scan ----------------
__global__ __launch_bounds__(256) void scan_bsum_k(const int* __restrict__ counts,
                                                   int* __restrict__ bsums) {
  __shared__ int wsum[4];
  int i = blockIdx.x * 256 + threadIdx.x;
  int v = (i < NN) ? counts[i] : 0;
#pragma unroll
  for (int off = 32; off; off >>= 1) v += __shfl_xor(v, off);
  if ((threadIdx.x & 63) == 0) wsum[threadIdx.x >> 6] = v;
  __syncthreads();
  if (threadIdx.x == 0) bsums[blockIdx.x] = wsum[0] + wsum[1] + wsum[2] + wsum[3];
}

__global__ __launch_bounds__(256) void scan_final_k(const int* __restrict__ counts,
                                                    const int* __restrict__ bsums,
                                                    int* __restrict__ offsets,
                                                    int* __restrict__ cursor) {
  __shared__ int s[256];
  __shared__ int wsum[4];
  __shared__ int bpref;
  int t = threadIdx.x;
  int bv = (t < NB && t < (int)blockIdx.x) ? bsums[t] : 0;
#pragma unroll
  for (int off = 32; off; off >>= 1) bv += __shfl_xor(bv, off);
  if ((t & 63) == 0) wsum[t >> 6] = bv;
  __syncthreads();
  if (t == 0) bpref = wsum[0] + wsum[1] + wsum[2] + wsum[3];
  int i = blockIdx.x * 256 + t;
  int v = (i < NN) ? counts[i] : 0;
  s[t] = v;
  __syncthreads();
  for (int off = 1; off < 256; off <<= 1) {
    int u = (t >= off) ? s[t - off] : 0;
    __syncthreads();
    s[t] += u;
    __syncthreads();
  }
  int excl = s[t] - v + bpref;
  if (i < NN) {
    offsets[i] = excl;
    cursor[i] = excl;
    if (i == NN - 1) offsets[NN] = excl + v;
  }
}

__global__ void scatter_k(const int* __restrict__ ei, int* __restrict__ cursor,
                          int2* __restrict__ csr) {
  int e = blockIdx.x * 256 + threadIdx.x;
  if (e >= NE) return;
  int s = ei[e], d = ei[NE + e];
  int pos = atomicAdd(&cursor[d], 1);
  csr[pos] = make_int2(s, e);
}

// ---------------- bf16 MFMA GEMM: C[M,N] = A[M,K] @ Bt[N,K]^T ----------------
template <int DOTS>
__global__ __launch_bounds__(256) void mgemm_k(
    const unsigned short* __restrict__ A, int lda,
    const unsigned short* __restrict__ Bt, int ldb,
    unsigned short* __restrict__ C, int ldc,
    int M, int N, int K,
    const float* __restrict__ ws, const float* __restrict__ wd,
    float* __restrict__ as_, float* __restrict__ ad_, int H) {
  __shared__ unsigned short Asl[64][40];
  __shared__ unsigned short Btl[64][40];
  __shared__ float sdot[64], ddot[64];
  int bm = blockIdx.y * 64, bn = blockIdx.x * 64;
  int t = threadIdx.x;
  int wv = t >> 6, lane = t & 63;
  int wm = (wv >> 1) * 32, wn = (wv & 1) * 32;
  int l16 = lane & 15, lq = lane >> 4;
  if (DOTS && t < 64) { sdot[t] = 0.f; ddot[t] = 0.f; }
  f4v acc[2][2];
#pragma unroll
  for (int mi = 0; mi < 2; ++mi)
#pragma unroll
    for (int ni = 0; ni < 2; ++ni) {
      acc[mi][ni][0] = 0.f; acc[mi][ni][1] = 0.f;
      acc[mi][ni][2] = 0.f; acc[mi][ni][3] = 0.f;
    }
  int sr = t >> 2, sc = (t & 3) * 8;
  for (int k0 = 0; k0 < K; k0 += 32) {
    uint4 av = {0, 0, 0, 0};
    int gr = bm + sr;
    if (gr < M) av = *(const uint4*)(A + (size_t)gr * lda + k0 + sc);
    *(uint4*)&Asl[sr][sc] = av;
    uint4 bv = *(const uint4*)(Bt + (size_t)(bn + sr) * ldb + k0 + sc);
    *(uint4*)&Btl[sr][sc] = bv;
    __syncthreads();
    s8v af[2], bfv[2];
#pragma unroll
    for (int mi = 0; mi < 2; ++mi)
      af[mi] = *(const s8v*)&Asl[wm + mi * 16 + l16][lq * 8];
#pragma unroll
    for (int ni = 0; ni < 2; ++ni)
      bfv[ni] = *(const s8v*)&Btl[wn + ni * 16 + l16][lq * 8];
#pragma unroll
    for (int mi = 0; mi < 2; ++mi)
#pragma unroll
      for (int ni = 0; ni < 2; ++ni)
        acc[mi][ni] = __builtin_amdgcn_mfma_f32_16x16x32_bf16(
            af[mi], bfv[ni], acc[mi][ni], 0, 0, 0);
    __syncthreads();
  }
#pragma unroll
  for (int mi = 0; mi < 2; ++mi)
#pragma unroll
    for (int rr = 0; rr < 4; ++rr) {
      int row = bm + wm + mi * 16 + lq * 4 + rr;
      if (row < M) {
#pragma unroll
        for (int ni = 0; ni < 2; ++ni) {
          int col = bn + wn + ni * 16 + l16;
          C[(size_t)row * ldc + col] = f2b(acc[mi][ni][rr]);
        }
      }
    }
  if (DOTS) {
    int head = blockIdx.x;
    float ps[2][4], pd[2][4];
#pragma unroll
    for (int mi = 0; mi < 2; ++mi)
#pragma unroll
      for (int rr = 0; rr < 4; ++rr) {
        float s = 0.f, d = 0.f;
#pragma unroll
        for (int ni = 0; ni < 2; ++ni) {
          int col = wn + ni * 16 + l16;
          s += acc[mi][ni][rr] * ws[head * 64 + col];
          d += acc[mi][ni][rr] * wd[head * 64 + col];
        }
        ps[mi][rr] = s;
        pd[mi][rr] = d;
      }
#pragma unroll
    for (int off = 1; off < 16; off <<= 1)
#pragma unroll
      for (int mi = 0; mi < 2; ++mi)
#pragma unroll
        for (int rr = 0; rr < 4; ++rr) {
          ps[mi][rr] += __shfl_xor(ps[mi][rr], off);
          pd[mi][rr] += __shfl_xor(pd[mi][rr], off);
        }
    if (l16 == 0) {
#pragma unroll
      for (int mi = 0; mi < 2; ++mi)
#pragma unroll
        for (int rr = 0; rr < 4; ++rr) {
          int rl = wm + mi * 16 + lq * 4 + rr;
          atomicAdd(&sdot[rl], ps[mi][rr]);
          atomicAdd(&ddot[rl], pd[mi][rr]);
        }
    }
    __syncthreads();
    if (t < 64 && bm + t < M) {
      as_[(size_t)(bm + t) * H + head] = sdot[t];
      ad_[(size_t)(bm + t) * H + head] = ddot[t];
    }
  }
}

// ---------------- GAT layer-1 aggregation: 1 wave per node, 4 heads -------
// 8-deep gather window (round-7 config: VGPR ~44, best measured).
__global__ __launch_bounds__(256) void gat_agg4_k(
    const int* __restrict__ offsets, const int2* __restrict__ csr,
    const unsigned short* __restrict__ h, const float* __restrict__ as_,
    const float* __restrict__ ad_, const float* __restrict__ bias,
    unsigned short* __restrict__ out) {
  __shared__ float exs[4][64][4];
  __shared__ int srcs[4][64];
  int wvx = threadIdx.x >> 6, lane = threadIdx.x & 63;
  int n = blockIdx.x * 4 + wvx;
  int hd = lane >> 4;
  int beg = offsets[n], end = offsets[n + 1];
  float4 adn = *(const float4*)(ad_ + (size_t)n * 4);
  float4 asn = *(const float4*)(as_ + (size_t)n * 4);
  float es0 = __expf(lrelu(asn.x + adn.x));
  float es1 = __expf(lrelu(asn.y + adn.y));
  float es2 = __expf(lrelu(asn.z + adn.z));
  float es3 = __expf(lrelu(asn.w + adn.w));
  float d0 = es0, d1 = es1, d2 = es2, d3 = es3;
  float wself = (hd == 0) ? es0 : (hd == 1) ? es1 : (hd == 2) ? es2 : es3;
  uint2 sv = *(const uint2*)(h + (size_t)n * 256 + lane * 4);
  float2 a01, a23;
  a01.x = wself * blo(sv.x); a01.y = wself * bhi(sv.x);
  a23.x = wself * blo(sv.y); a23.y = wself * bhi(sv.y);
  for (int base = beg; base < end; base += 64) {
    int cnt = min(64, end - base);
    int src = 0;
    float e0 = 0.f, e1 = 0.f, e2 = 0.f, e3 = 0.f;
    if (lane < cnt) {
      src = csr[base + lane].x;
      float4 a4 = *(const float4*)(as_ + (size_t)src * 4);
      e0 = __expf(lrelu(a4.x + adn.x));
      e1 = __expf(lrelu(a4.y + adn.y));
      e2 = __expf(lrelu(a4.z + adn.z));
      e3 = __expf(lrelu(a4.w + adn.w));
    }
    float s0 = e0, s1 = e1, s2 = e2, s3 = e3;
#pragma unroll
    for (int off = 32; off; off >>= 1) {
      s0 += __shfl_xor(s0, off);
      s1 += __shfl_xor(s1, off);
      s2 += __shfl_xor(s2, off);
      s3 += __shfl_xor(s3, off);
    }
    d0 += s0; d1 += s1; d2 += s2; d3 += s3;
    float4 ex4 = {e0, e1, e2, e3};
    *(float4*)(&exs[wvx][lane][0]) = ex4;
    srcs[wvx][lane] = src;
    __builtin_amdgcn_wave_barrier();
    int e = 0;
    for (; e + 8 <= cnt; e += 8) {
      uint2 r[8];
      float w[8];
#pragma unroll
      for (int j = 0; j < 8; ++j) {
        int si = srcs[wvx][e + j];
        w[j] = exs[wvx][e + j][hd];
        r[j] = *(const uint2*)(h + (size_t)si * 256 + lane * 4);
      }
#pragma unroll
      for (int j = 0; j < 8; ++j) {
        a01.x += w[j] * blo(r[j].x); a01.y += w[j] * bhi(r[j].x);
        a23.x += w[j] * blo(r[j].y); a23.y += w[j] * bhi(r[j].y);
      }
    }
    for (; e < cnt; ++e) {
      int si = srcs[wvx][e];
      float w = exs[wvx][e][hd];
      uint2 r = *(const uint2*)(h + (size_t)si * 256 + lane * 4);
      a01.x += w * blo(r.x); a01.y += w * bhi(r.x);
      a23.x += w * blo(r.y); a23.y += w * bhi(r.y);
    }
  }
  float myden = (hd == 0) ? d0 : (hd == 1) ? d1 : (hd == 2) ? d2 : d3;
  float inv = 1.f / myden;
  float4 b4 = *(const float4*)(bias + lane * 4);
  float4 res;
  res.x = a01.x * inv + b4.x;
  res.y = a01.y * inv + b4.y;
  res.z = a23.x * inv + b4.z;
  res.w = a23.y * inv + b4.w;
  res.x = (res.x > 0.f) ? res.x : (__expf(res.x) - 1.f);
  res.y = (res.y > 0.f) ? res.y : (__expf(res.y) - 1.f);
  res.z = (res.z > 0.f) ? res.z : (__expf(res.z) - 1.f);
  res.w = (res.w > 0.f) ? res.w : (__expf(res.w) - 1.f);
  ushort4 ov = {f2b(res.x), f2b(res.y), f2b(res.z), f2b(res.w)};
  *(ushort4*)(out + (size_t)n * 256 + lane * 4) = ov;
}

// ---------------- GAT layer-2 aggregation + fused pq projection -----------
// 4 slots x 16 lanes x 4 ch; after cross-slot reduce, the y row (fp32) is
// staged in LDS and each lane computes p[lane] = y.mw1[:, lane], q[lane].
__global__ __launch_bounds__(256) void gat_agg1_k(
    const int* __restrict__ offsets, const int2* __restrict__ csr,
    const unsigned short* __restrict__ h, const float* __restrict__ as_,
    const float* __restrict__ ad_, const float* __restrict__ bias,
    const unsigned short* __restrict__ pqt, unsigned short* __restrict__ pqo) {
  __shared__ float exs[4][64];
  __shared__ int srcs[4][64];
  __shared__ float ych[4][64];
  int wvx = threadIdx.x >> 6, lane = threadIdx.x & 63;
  int n = blockIdx.x * 4 + wvx;
  int slot = lane >> 4, cp = lane & 15;
  int beg = offsets[n], end = offsets[n + 1];
  float adn = ad_[n];
  float eself = __expf(lrelu(as_[n] + adn));
  float den = eself;
  float2 a01 = {0.f, 0.f}, a23 = {0.f, 0.f};
  if (slot == 0) {
    uint2 sv = *(const uint2*)(h + (size_t)n * 64 + cp * 4);
    a01.x = eself * blo(sv.x); a01.y = eself * bhi(sv.x);
    a23.x = eself * blo(sv.y); a23.y = eself * bhi(sv.y);
  }
  for (int base = beg; base < end; base += 64) {
    int cnt = min(64, end - base);
    int src = 0;
    float ex = 0.f;
    if (lane < cnt) {
      src = csr[base + lane].x;
      ex = __expf(lrelu(as_[src] + adn));
    }
    float s = ex;
#pragma unroll
    for (int off = 32; off; off >>= 1) s += __shfl_xor(s, off);
    den += s;
    exs[wvx][lane] = ex;
    srcs[wvx][lane] = src;
    __builtin_amdgcn_wave_barrier();
    int i = slot;
    for (; i + 12 < cnt; i += 16) {
      uint2 r[4];
      int i0 = i, i1 = i + 4, i2 = i + 8, i3 = i + 12;
      r[0] = *(const uint2*)(h + (size_t)srcs[wvx][i0] * 64 + cp * 4);
      r[1] = *(const uint2*)(h + (size_t)srcs[wvx][i1] * 64 + cp * 4);
      r[2] = *(const uint2*)(h + (size_t)srcs[wvx][i2] * 64 + cp * 4);
      r[3] = *(const uint2*)(h + (size_t)srcs[wvx][i3] * 64 + cp * 4);
      float w0 = exs[wvx][i0], w1 = exs[wvx][i1], w2 = exs[wvx][i2], w3 = exs[wvx][i3];
      a01.x += w0 * blo(r[0].x); a01.y += w0 * bhi(r[0].x);
      a23.x += w0 * blo(r[0].y); a23.y += w0 * bhi(r[0].y);
      a01.x += w1 * blo(r[1].x); a01.y += w1 * bhi(r[1].x);
      a23.x += w1 * blo(r[1].y); a23.y += w1 * bhi(r[1].y);
      a01.x += w2 * blo(r[2].x); a01.y += w2 * bhi(r[2].x);
      a23.x += w2 * blo(r[2].y); a23.y += w2 * bhi(r[2].y);
      a01.x += w3 * blo(r[3].x); a01.y += w3 * bhi(r[3].x);
      a23.x += w3 * blo(r[3].y); a23.y += w3 * bhi(r[3].y);
    }
    for (; i < cnt; i += 4) {
      int si = srcs[wvx][i];
      float w = exs[wvx][i];
      uint2 r = *(const uint2*)(h + (size_t)si * 64 + cp * 4);
      a01.x += w * blo(r.x); a01.y += w * bhi(r.x);
      a23.x += w * blo(r.y); a23.y += w * bhi(r.y);
    }
  }
#pragma unroll
  for (int off = 16; off <= 32; off <<= 1) {
    a01.x += __shfl_xor(a01.x, off);
    a01.y += __shfl_xor(a01.y, off);
    a23.x += __shfl_xor(a23.x, off);
    a23.y += __shfl_xor(a23.y, off);
  }
  // stage y row (fp32) in LDS
  if (slot == 0) {
    float inv = 1.f / den;
    float4 b4 = *(const float4*)(bias + cp * 4);
    float4 yv;
    yv.x = a01.x * inv + b4.x;
    yv.y = a01.y * inv + b4.y;
    yv.z = a23.x * inv + b4.z;
    yv.w = a23.y * inv + b4.w;
    *(float4*)(&ych[wvx][cp * 4]) = yv;
  }
  __builtin_amdgcn_wave_barrier();
  // fused pq projection: lane computes p[lane] and q[lane] (dot-64 each)
  float accp = 0.f, accq = 0.f;
  const unsigned short* wp = pqt + (size_t)lane * 64;
  const unsigned short* wq = pqt + (size_t)(lane + 64) * 64;
#pragma unroll
  for (int k = 0; k < 64; k += 8) {
    uint4 wpv = *(const uint4*)(wp + k);
    uint4 wqv = *(const uint4*)(wq + k);
    float4 y0 = *(const float4*)(&ych[wvx][k]);
    float4 y1 = *(const float4*)(&ych[wvx][k + 4]);
    accp += y0.x * blo(wpv.x) + y0.y * bhi(wpv.x) + y0.z * blo(wpv.y) + y0.w * bhi(wpv.y)
          + y1.x * blo(wpv.z) + y1.y * bhi(wpv.z) + y1.z * blo(wpv.w) + y1.w * bhi(wpv.w);
    accq += y0.x * blo(wqv.x) + y0.y * bhi(wqv.x) + y0.z * blo(wqv.y) + y0.w * bhi(wqv.y)
          + y1.x * blo(wqv.z) + y1.y * bhi(wqv.z) + y1.z * blo(wqv.w) + y1.w * bhi(wqv.w);
  }
  pqo[(size_t)n * 128 + lane] = f2b(accp);
  pqo[(size_t)n * 128 + 64 + lane] = f2b(accq);
}

// ---------------- dst-grouped edge MLP: 1 wave per dst node ---------------
__global__ __launch_bounds__(256) void edge_out_k(
    const int* __restrict__ offsets, const int2* __restrict__ csr,
    const unsigned short* __restrict__ pq,
    const float* __restrict__ mb1, const float* __restrict__ w2,
    const float* __restrict__ mb2, float* __restrict__ out) {
  int wvx = threadIdx.x >> 6, lane = threadIdx.x & 63;
  int n = blockIdx.x * 4 + wvx;
  int slot = lane >> 4, cp = lane & 15;
  int beg = offsets[n], end = offsets[n + 1];
  ushort4 qv = *(const ushort4*)(pq + (size_t)n * 128 + 64 + cp * 4);
  float4 base4 = *(const float4*)(mb1 + cp * 4);
  base4.x += bf2f(qv.x); base4.y += bf2f(qv.y);
  base4.z += bf2f(qv.z); base4.w += bf2f(qv.w);
  float4 w4 = *(const float4*)(w2 + cp * 4);
  float b2v = mb2[0];
  for (int base = beg; base < end; base += 4) {
    int i = base + slot;
    int2 se = {0, 0};
    bool ok = (i < end);
    if (ok) se = csr[i];
    float r = 0.f;
    if (ok) {
      ushort4 pv = *(const ushort4*)(pq + (size_t)se.x * 128 + cp * 4);
      float v0 = fmaxf(bf2f(pv.x) + base4.x, 0.f);
      float v1 = fmaxf(bf2f(pv.y) + base4.y, 0.f);
      float v2 = fmaxf(bf2f(pv.z) + base4.z, 0.f);
      float v3 = fmaxf(bf2f(pv.w) + base4.w, 0.f);
      r = v0 * w4.x + v1 * w4.y + v2 * w4.z + v3 * w4.w;
    }
    r += __shfl_xor(r, 8);
    r += __shfl_xor(r, 4);
    r += __shfl_xor(r, 2);
    r += __shfl_xor(r, 1);
    if (cp == 0 && ok) out[se.y] = r + b2v;
  }
}

extern "C" void kernel_launch(void* const* d_in, const int* in_sizes, int n_in,
                              void* d_out, int out_size, void* d_ws, size_t ws_size,
                              hipStream_t stream) {
  const float* x = (const float*)d_in[0];
  const int* ei = (const int*)d_in[1];
  const float* W1 = (const float*)d_in[2];
  const float* as1w = (const float*)d_in[3];
  const float* ad1w = (const float*)d_in[4];
  const float* b1 = (const float*)d_in[5];
  const float* W2 = (const float*)d_in[6];
  const float* as2w = (const float*)d_in[7];
  const float* ad2w = (const float*)d_in[8];
  const float* b2 = (const float*)d_in[9];
  const float* mw1 = (const float*)d_in[10];
  const float* mb1 = (const float*)d_in[11];
  const float* mw2 = (const float*)d_in[12];
  const float* mb2 = (const float*)d_in[13];
  float* out = (float*)d_out;

  char* ws = (char*)d_ws;
  size_t o = 0;
  auto alloc = [&](size_t bytes) {
    void* ptr = ws + o;
    o += (bytes + 255) & ~(size_t)255;
    return ptr;
  };
  int* counts = (int*)alloc((size_t)NN * 4);
  int* offsets = (int*)alloc((size_t)(NN + 1) * 4);
  int* cursor = (int*)alloc((size_t)NN * 4);
  int* bsums = (int*)alloc((size_t)NB * 4);
  int2* csr = (int2*)alloc((size_t)NE * 8);
  unsigned short* xb = (unsigned short*)alloc((size_t)NN * 128 * 2);
  unsigned short* w1t = (unsigned short*)alloc((size_t)256 * 128 * 2);
  unsigned short* w2t = (unsigned short*)alloc((size_t)64 * 256 * 2);
  unsigned short* pqt = (unsigned short*)alloc((size_t)128 * 64 * 2);
  unsigned short* h1b = (unsigned short*)alloc((size_t)NN * 256 * 2);  // reused h2b/pq
  float* a_s1 = (float*)alloc((size_t)NN * 4 * 4);
  float* a_d1 = (float*)alloc((size_t)NN * 4 * 4);
  unsigned short* x2b = (unsigned short*)alloc((size_t)NN * 256 * 2);
  unsigned short* h2b = h1b;                  // NN*64
  unsigned short* pq = h1b + (size_t)NN * 64; // NN*128, [p|q]

  // CSR build + conversions
  hipMemsetAsync(counts, 0, (size_t)NN * 4, stream);
  prep_k<<<NHB + (NX4 + NW1 + NW2 + NPQ + 255) / 256, 256, 0, stream>>>(
      ei, counts, x, W1, W2, mw1, xb, w1t, w2t, pqt);
  scan_bsum_k<<<NB, 256, 0, stream>>>(counts, bsums);
  scan_final_k<<<NB, 256, 0, stream>>>(counts, bsums, offsets, cursor);
  scatter_k<<<(NE + 255) / 256, 256, 0, stream>>>(ei, cursor, csr);

  int gy = (NN + 63) / 64;
  // Layer 1: h1 = x @ W1 (MFMA, bf16) + fused dots; aggregate -> x2 (bf16)
  mgemm_k<1><<<dim3(4, gy), 256, 0, stream>>>(xb, 128, w1t, 128, h1b, 256,
                                              NN, 256, 128, as1w, ad1w, a_s1, a_d1, 4);
  gat_agg4_k<<<NN / 4, 256, 0, stream>>>(offsets, csr, h1b, a_s1, a_d1, b1, x2b);

  // Layer 2: h2 = x2 @ W2 (MFMA) + fused dots; aggregate+pq-project fused
  mgemm_k<1><<<dim3(1, gy), 256, 0, stream>>>(x2b, 256, w2t, 256, h2b, 64,
                                              NN, 64, 256, as2w, ad2w, a_s1, a_d1, 1);
  gat_agg1_k<<<NN / 4, 256, 0, stream>>>(offsets, csr, h2b, a_s1, a_d1, b2, pqt, pq);

  // Final per-edge output (dst-grouped)
  edge_out_k<<<NN / 4, 256, 0, stream>>>(offsets, csr, pq, mb1, mw2, mb2, out);
}

// Round 10
// 285.239 us; speedup vs baseline: 1.2714x; 1.2714x over previous
//
#include <hip/hip_runtime.h>
#include <hip/hip_bf16.h>
#include <math.h>

#define NN 50000
#define NE 800000
#define NB ((NN + 255) / 256)
#define NEG 0.2f
#define NHB ((NE + 255) / 256)

typedef __hip_bfloat16 bf16;
typedef __attribute__((ext_vector_type(8))) short s8v;
typedef __attribute__((ext_vector_type(4))) float f4v;

__device__ __forceinline__ float bf2f(unsigned short u) {
  union { unsigned int i; float f; } c;
  c.i = ((unsigned int)u) << 16;
  return c.f;
}
__device__ __forceinline__ float blo(unsigned int u) {
  union { unsigned int i; float f; } c;
  c.i = u << 16;
  return c.f;
}
__device__ __forceinline__ float bhi(unsigned int u) {
  union { unsigned int i; float f; } c;
  c.i = u & 0xffff0000u;
  return c.f;
}
__device__ __forceinline__ unsigned short f2b(float f) {
  bf16 b = __float2bfloat16(f);
  return __builtin_bit_cast(unsigned short, b);
}
__device__ __forceinline__ float lrelu(float t) { return (t > 0.f) ? t : NEG * t; }

// ---------------- prep: histogram + all fp32->bf16 conversions -------------
#define NX4 (NN * 32)           // x as float4 units
#define NW1 (256 * 128)
#define NW2 (64 * 256)
#define NPQ (128 * 64)
__global__ void prep_k(const int* __restrict__ ei, int* __restrict__ counts,
                       const float* __restrict__ x, const float* __restrict__ W1,
                       const float* __restrict__ W2, const float* __restrict__ mw1,
                       unsigned short* __restrict__ xb, unsigned short* __restrict__ w1t,
                       unsigned short* __restrict__ w2t, unsigned short* __restrict__ pqt) {
  int b = blockIdx.x;
  if (b < NHB) {
    int e = b * 256 + threadIdx.x;
    if (e < NE) atomicAdd(&counts[ei[NE + e]], 1);
    return;
  }
  int i = (b - NHB) * 256 + threadIdx.x;
  if (i < NX4) {
    float4 v = *(const float4*)(x + (size_t)i * 4);
    ushort4 o = {f2b(v.x), f2b(v.y), f2b(v.z), f2b(v.w)};
    *(ushort4*)(xb + (size_t)i * 4) = o;
    return;
  }
  i -= NX4;
  if (i < NW1) {  // w1t[n*128+k] = W1[k*256+n]
    int n = i >> 7, k = i & 127;
    w1t[i] = f2b(W1[(size_t)k * 256 + n]);
    return;
  }
  i -= NW1;
  if (i < NW2) {  // w2t[n*256+k] = W2[k*64+n]
    int n = i >> 8, k = i & 255;
    w2t[i] = f2b(W2[(size_t)k * 64 + n]);
    return;
  }
  i -= NW2;
  if (i < NPQ) {
    int n = i >> 6, k = i & 63;
    float v = (n < 64) ? mw1[(size_t)k * 64 + n] : mw1[(size_t)(64 + k) * 64 + (n - 64)];
    pqt[i] = f2b(v);
  }
}

// ---------------- scan ----------------
__global__ __launch_bounds__(256) void scan_bsum_k(const int* __restrict__ counts,
                                                   int* __restrict__ bsums) {
  __shared__ int wsum[4];
  int i = blockIdx.x * 256 + threadIdx.x;
  int v = (i < NN) ? counts[i] : 0;
#pragma unroll
  for (int off = 32; off; off >>= 1) v += __shfl_xor(v, off);
  if ((threadIdx.x & 63) == 0) wsum[threadIdx.x >> 6] = v;
  __syncthreads();
  if (threadIdx.x == 0) bsums[blockIdx.x] = wsum[0] + wsum[1] + wsum[2] + wsum[3];
}

__global__ __launch_bounds__(256) void scan_final_k(const int* __restrict__ counts,
                                                    const int* __restrict__ bsums,
                                                    int* __restrict__ offsets,
                                                    int* __restrict__ cursor) {
  __shared__ int s[256];
  __shared__ int wsum[4];
  __shared__ int bpref;
  int t = threadIdx.x;
  int bv = (t < NB && t < (int)blockIdx.x) ? bsums[t] : 0;
#pragma unroll
  for (int off = 32; off; off >>= 1) bv += __shfl_xor(bv, off);
  if ((t & 63) == 0) wsum[t >> 6] = bv;
  __syncthreads();
  if (t == 0) bpref = wsum[0] + wsum[1] + wsum[2] + wsum[3];
  int i = blockIdx.x * 256 + t;
  int v = (i < NN) ? counts[i] : 0;
  s[t] = v;
  __syncthreads();
  for (int off = 1; off < 256; off <<= 1) {
    int u = (t >= off) ? s[t - off] : 0;
    __syncthreads();
    s[t] += u;
    __syncthreads();
  }
  int excl = s[t] - v + bpref;
  if (i < NN) {
    offsets[i] = excl;
    cursor[i] = excl;
    if (i == NN - 1) offsets[NN] = excl + v;
  }
}

__global__ void scatter_k(const int* __restrict__ ei, int* __restrict__ cursor,
                          int2* __restrict__ csr) {
  int e = blockIdx.x * 256 + threadIdx.x;
  if (e >= NE) return;
  int s = ei[e], d = ei[NE + e];
  int pos = atomicAdd(&cursor[d], 1);
  csr[pos] = make_int2(s, e);
}

// ---------------- bf16 MFMA GEMM: C[M,N] = A[M,K] @ Bt[N,K]^T ----------------
template <int DOTS>
__global__ __launch_bounds__(256) void mgemm_k(
    const unsigned short* __restrict__ A, int lda,
    const unsigned short* __restrict__ Bt, int ldb,
    unsigned short* __restrict__ C, int ldc,
    int M, int N, int K,
    const float* __restrict__ ws, const float* __restrict__ wd,
    float* __restrict__ as_, float* __restrict__ ad_, int H) {
  __shared__ unsigned short Asl[64][40];
  __shared__ unsigned short Btl[64][40];
  __shared__ float sdot[64], ddot[64];
  int bm = blockIdx.y * 64, bn = blockIdx.x * 64;
  int t = threadIdx.x;
  int wv = t >> 6, lane = t & 63;
  int wm = (wv >> 1) * 32, wn = (wv & 1) * 32;
  int l16 = lane & 15, lq = lane >> 4;
  if (DOTS && t < 64) { sdot[t] = 0.f; ddot[t] = 0.f; }
  f4v acc[2][2];
#pragma unroll
  for (int mi = 0; mi < 2; ++mi)
#pragma unroll
    for (int ni = 0; ni < 2; ++ni) {
      acc[mi][ni][0] = 0.f; acc[mi][ni][1] = 0.f;
      acc[mi][ni][2] = 0.f; acc[mi][ni][3] = 0.f;
    }
  int sr = t >> 2, sc = (t & 3) * 8;
  for (int k0 = 0; k0 < K; k0 += 32) {
    uint4 av = {0, 0, 0, 0};
    int gr = bm + sr;
    if (gr < M) av = *(const uint4*)(A + (size_t)gr * lda + k0 + sc);
    *(uint4*)&Asl[sr][sc] = av;
    uint4 bv = *(const uint4*)(Bt + (size_t)(bn + sr) * ldb + k0 + sc);
    *(uint4*)&Btl[sr][sc] = bv;
    __syncthreads();
    s8v af[2], bfv[2];
#pragma unroll
    for (int mi = 0; mi < 2; ++mi)
      af[mi] = *(const s8v*)&Asl[wm + mi * 16 + l16][lq * 8];
#pragma unroll
    for (int ni = 0; ni < 2; ++ni)
      bfv[ni] = *(const s8v*)&Btl[wn + ni * 16 + l16][lq * 8];
#pragma unroll
    for (int mi = 0; mi < 2; ++mi)
#pragma unroll
      for (int ni = 0; ni < 2; ++ni)
        acc[mi][ni] = __builtin_amdgcn_mfma_f32_16x16x32_bf16(
            af[mi], bfv[ni], acc[mi][ni], 0, 0, 0);
    __syncthreads();
  }
#pragma unroll
  for (int mi = 0; mi < 2; ++mi)
#pragma unroll
    for (int rr = 0; rr < 4; ++rr) {
      int row = bm + wm + mi * 16 + lq * 4 + rr;
      if (row < M) {
#pragma unroll
        for (int ni = 0; ni < 2; ++ni) {
          int col = bn + wn + ni * 16 + l16;
          C[(size_t)row * ldc + col] = f2b(acc[mi][ni][rr]);
        }
      }
    }
  if (DOTS) {
    int head = blockIdx.x;
    float ps[2][4], pd[2][4];
#pragma unroll
    for (int mi = 0; mi < 2; ++mi)
#pragma unroll
      for (int rr = 0; rr < 4; ++rr) {
        float s = 0.f, d = 0.f;
#pragma unroll
        for (int ni = 0; ni < 2; ++ni) {
          int col = wn + ni * 16 + l16;
          s += acc[mi][ni][rr] * ws[head * 64 + col];
          d += acc[mi][ni][rr] * wd[head * 64 + col];
        }
        ps[mi][rr] = s;
        pd[mi][rr] = d;
      }
#pragma unroll
    for (int off = 1; off < 16; off <<= 1)
#pragma unroll
      for (int mi = 0; mi < 2; ++mi)
#pragma unroll
        for (int rr = 0; rr < 4; ++rr) {
          ps[mi][rr] += __shfl_xor(ps[mi][rr], off);
          pd[mi][rr] += __shfl_xor(pd[mi][rr], off);
        }
    if (l16 == 0) {
#pragma unroll
      for (int mi = 0; mi < 2; ++mi)
#pragma unroll
        for (int rr = 0; rr < 4; ++rr) {
          int rl = wm + mi * 16 + lq * 4 + rr;
          atomicAdd(&sdot[rl], ps[mi][rr]);
          atomicAdd(&ddot[rl], pd[mi][rr]);
        }
    }
    __syncthreads();
    if (t < 64 && bm + t < M) {
      as_[(size_t)(bm + t) * H + head] = sdot[t];
      ad_[(size_t)(bm + t) * H + head] = ddot[t];
    }
  }
}

// ---------------- GAT layer-1 aggregation: 1 wave per node, 4 heads -------
// 8-deep gather window (round-7 config: VGPR ~44, best measured).
__global__ __launch_bounds__(256) void gat_agg4_k(
    const int* __restrict__ offsets, const int2* __restrict__ csr,
    const unsigned short* __restrict__ h, const float* __restrict__ as_,
    const float* __restrict__ ad_, const float* __restrict__ bias,
    unsigned short* __restrict__ out) {
  __shared__ float exs[4][64][4];
  __shared__ int srcs[4][64];
  int wvx = threadIdx.x >> 6, lane = threadIdx.x & 63;
  int n = blockIdx.x * 4 + wvx;
  int hd = lane >> 4;
  int beg = offsets[n], end = offsets[n + 1];
  float4 adn = *(const float4*)(ad_ + (size_t)n * 4);
  float4 asn = *(const float4*)(as_ + (size_t)n * 4);
  float es0 = __expf(lrelu(asn.x + adn.x));
  float es1 = __expf(lrelu(asn.y + adn.y));
  float es2 = __expf(lrelu(asn.z + adn.z));
  float es3 = __expf(lrelu(asn.w + adn.w));
  float d0 = es0, d1 = es1, d2 = es2, d3 = es3;
  float wself = (hd == 0) ? es0 : (hd == 1) ? es1 : (hd == 2) ? es2 : es3;
  uint2 sv = *(const uint2*)(h + (size_t)n * 256 + lane * 4);
  float2 a01, a23;
  a01.x = wself * blo(sv.x); a01.y = wself * bhi(sv.x);
  a23.x = wself * blo(sv.y); a23.y = wself * bhi(sv.y);
  for (int base = beg; base < end; base += 64) {
    int cnt = min(64, end - base);
    int src = 0;
    float e0 = 0.f, e1 = 0.f, e2 = 0.f, e3 = 0.f;
    if (lane < cnt) {
      src = csr[base + lane].x;
      float4 a4 = *(const float4*)(as_ + (size_t)src * 4);
      e0 = __expf(lrelu(a4.x + adn.x));
      e1 = __expf(lrelu(a4.y + adn.y));
      e2 = __expf(lrelu(a4.z + adn.z));
      e3 = __expf(lrelu(a4.w + adn.w));
    }
    float s0 = e0, s1 = e1, s2 = e2, s3 = e3;
#pragma unroll
    for (int off = 32; off; off >>= 1) {
      s0 += __shfl_xor(s0, off);
      s1 += __shfl_xor(s1, off);
      s2 += __shfl_xor(s2, off);
      s3 += __shfl_xor(s3, off);
    }
    d0 += s0; d1 += s1; d2 += s2; d3 += s3;
    float4 ex4 = {e0, e1, e2, e3};
    *(float4*)(&exs[wvx][lane][0]) = ex4;
    srcs[wvx][lane] = src;
    __builtin_amdgcn_wave_barrier();
    int e = 0;
    for (; e + 8 <= cnt; e += 8) {
      uint2 r[8];
      float w[8];
#pragma unroll
      for (int j = 0; j < 8; ++j) {
        int si = srcs[wvx][e + j];
        w[j] = exs[wvx][e + j][hd];
        r[j] = *(const uint2*)(h + (size_t)si * 256 + lane * 4);
      }
#pragma unroll
      for (int j = 0; j < 8; ++j) {
        a01.x += w[j] * blo(r[j].x); a01.y += w[j] * bhi(r[j].x);
        a23.x += w[j] * blo(r[j].y); a23.y += w[j] * bhi(r[j].y);
      }
    }
    for (; e < cnt; ++e) {
      int si = srcs[wvx][e];
      float w = exs[wvx][e][hd];
      uint2 r = *(const uint2*)(h + (size_t)si * 256 + lane * 4);
      a01.x += w * blo(r.x); a01.y += w * bhi(r.x);
      a23.x += w * blo(r.y); a23.y += w * bhi(r.y);
    }
  }
  float myden = (hd == 0) ? d0 : (hd == 1) ? d1 : (hd == 2) ? d2 : d3;
  float inv = 1.f / myden;
  float4 b4 = *(const float4*)(bias + lane * 4);
  float4 res;
  res.x = a01.x * inv + b4.x;
  res.y = a01.y * inv + b4.y;
  res.z = a23.x * inv + b4.z;
  res.w = a23.y * inv + b4.w;
  res.x = (res.x > 0.f) ? res.x : (__expf(res.x) - 1.f);
  res.y = (res.y > 0.f) ? res.y : (__expf(res.y) - 1.f);
  res.z = (res.z > 0.f) ? res.z : (__expf(res.z) - 1.f);
  res.w = (res.w > 0.f) ? res.w : (__expf(res.w) - 1.f);
  ushort4 ov = {f2b(res.x), f2b(res.y), f2b(res.z), f2b(res.w)};
  *(ushort4*)(out + (size_t)n * 256 + lane * 4) = ov;
}

// ---------------- GAT layer-2 aggregation: 1 wave per node, H=1 ----------
// 4 slots x 16 lanes x 4 ch (ushort4); 2-step cross-slot reduce. Writes yb.
__global__ __launch_bounds__(256) void gat_agg1_k(
    const int* __restrict__ offsets, const int2* __restrict__ csr,
    const unsigned short* __restrict__ h, const float* __restrict__ as_,
    const float* __restrict__ ad_, const float* __restrict__ bias,
    unsigned short* __restrict__ out) {
  __shared__ float exs[4][64];
  __shared__ int srcs[4][64];
  int wvx = threadIdx.x >> 6, lane = threadIdx.x & 63;
  int n = blockIdx.x * 4 + wvx;
  int slot = lane >> 4, cp = lane & 15;
  int beg = offsets[n], end = offsets[n + 1];
  float adn = ad_[n];
  float eself = __expf(lrelu(as_[n] + adn));
  float den = eself;
  float2 a01 = {0.f, 0.f}, a23 = {0.f, 0.f};
  if (slot == 0) {
    uint2 sv = *(const uint2*)(h + (size_t)n * 64 + cp * 4);
    a01.x = eself * blo(sv.x); a01.y = eself * bhi(sv.x);
    a23.x = eself * blo(sv.y); a23.y = eself * bhi(sv.y);
  }
  for (int base = beg; base < end; base += 64) {
    int cnt = min(64, end - base);
    int src = 0;
    float ex = 0.f;
    if (lane < cnt) {
      src = csr[base + lane].x;
      ex = __expf(lrelu(as_[src] + adn));
    }
    float s = ex;
#pragma unroll
    for (int off = 32; off; off >>= 1) s += __shfl_xor(s, off);
    den += s;
    exs[wvx][lane] = ex;
    srcs[wvx][lane] = src;
    __builtin_amdgcn_wave_barrier();
    int i = slot;
    for (; i + 12 < cnt; i += 16) {
      uint2 r[4];
      int i0 = i, i1 = i + 4, i2 = i + 8, i3 = i + 12;
      r[0] = *(const uint2*)(h + (size_t)srcs[wvx][i0] * 64 + cp * 4);
      r[1] = *(const uint2*)(h + (size_t)srcs[wvx][i1] * 64 + cp * 4);
      r[2] = *(const uint2*)(h + (size_t)srcs[wvx][i2] * 64 + cp * 4);
      r[3] = *(const uint2*)(h + (size_t)srcs[wvx][i3] * 64 + cp * 4);
      float w0 = exs[wvx][i0], w1 = exs[wvx][i1], w2 = exs[wvx][i2], w3 = exs[wvx][i3];
      a01.x += w0 * blo(r[0].x); a01.y += w0 * bhi(r[0].x);
      a23.x += w0 * blo(r[0].y); a23.y += w0 * bhi(r[0].y);
      a01.x += w1 * blo(r[1].x); a01.y += w1 * bhi(r[1].x);
      a23.x += w1 * blo(r[1].y); a23.y += w1 * bhi(r[1].y);
      a01.x += w2 * blo(r[2].x); a01.y += w2 * bhi(r[2].x);
      a23.x += w2 * blo(r[2].y); a23.y += w2 * bhi(r[2].y);
      a01.x += w3 * blo(r[3].x); a01.y += w3 * bhi(r[3].x);
      a23.x += w3 * blo(r[3].y); a23.y += w3 * bhi(r[3].y);
    }
    for (; i < cnt; i += 4) {
      int si = srcs[wvx][i];
      float w = exs[wvx][i];
      uint2 r = *(const uint2*)(h + (size_t)si * 64 + cp * 4);
      a01.x += w * blo(r.x); a01.y += w * bhi(r.x);
      a23.x += w * blo(r.y); a23.y += w * bhi(r.y);
    }
  }
#pragma unroll
  for (int off = 16; off <= 32; off <<= 1) {
    a01.x += __shfl_xor(a01.x, off);
    a01.y += __shfl_xor(a01.y, off);
    a23.x += __shfl_xor(a23.x, off);
    a23.y += __shfl_xor(a23.y, off);
  }
  if (slot == 0) {
    float inv = 1.f / den;
    float4 b4 = *(const float4*)(bias + cp * 4);
    ushort4 ov;
    ov.x = f2b(a01.x * inv + b4.x);
    ov.y = f2b(a01.y * inv + b4.y);
    ov.z = f2b(a23.x * inv + b4.z);
    ov.w = f2b(a23.y * inv + b4.w);
    *(ushort4*)(out + (size_t)n * 64 + cp * 4) = ov;
  }
}

// ---------------- dst-grouped edge MLP: 1 wave per dst node ---------------
__global__ __launch_bounds__(256) void edge_out_k(
    const int* __restrict__ offsets, const int2* __restrict__ csr,
    const unsigned short* __restrict__ pq,
    const float* __restrict__ mb1, const float* __restrict__ w2,
    const float* __restrict__ mb2, float* __restrict__ out) {
  int wvx = threadIdx.x >> 6, lane = threadIdx.x & 63;
  int n = blockIdx.x * 4 + wvx;
  int slot = lane >> 4, cp = lane & 15;
  int beg = offsets[n], end = offsets[n + 1];
  ushort4 qv = *(const ushort4*)(pq + (size_t)n * 128 + 64 + cp * 4);
  float4 base4 = *(const float4*)(mb1 + cp * 4);
  base4.x += bf2f(qv.x); base4.y += bf2f(qv.y);
  base4.z += bf2f(qv.z); base4.w += bf2f(qv.w);
  float4 w4 = *(const float4*)(w2 + cp * 4);
  float b2v = mb2[0];
  for (int base = beg; base < end; base += 4) {
    int i = base + slot;
    int2 se = {0, 0};
    bool ok = (i < end);
    if (ok) se = csr[i];
    float r = 0.f;
    if (ok) {
      ushort4 pv = *(const ushort4*)(pq + (size_t)se.x * 128 + cp * 4);
      float v0 = fmaxf(bf2f(pv.x) + base4.x, 0.f);
      float v1 = fmaxf(bf2f(pv.y) + base4.y, 0.f);
      float v2 = fmaxf(bf2f(pv.z) + base4.z, 0.f);
      float v3 = fmaxf(bf2f(pv.w) + base4.w, 0.f);
      r = v0 * w4.x + v1 * w4.y + v2 * w4.z + v3 * w4.w;
    }
    r += __shfl_xor(r, 8);
    r += __shfl_xor(r, 4);
    r += __shfl_xor(r, 2);
    r += __shfl_xor(r, 1);
    if (cp == 0 && ok) out[se.y] = r + b2v;
  }
}

extern "C" void kernel_launch(void* const* d_in, const int* in_sizes, int n_in,
                              void* d_out, int out_size, void* d_ws, size_t ws_size,
                              hipStream_t stream) {
  const float* x = (const float*)d_in[0];
  const int* ei = (const int*)d_in[1];
  const float* W1 = (const float*)d_in[2];
  const float* as1w = (const float*)d_in[3];
  const float* ad1w = (const float*)d_in[4];
  const float* b1 = (const float*)d_in[5];
  const float* W2 = (const float*)d_in[6];
  const float* as2w = (const float*)d_in[7];
  const float* ad2w = (const float*)d_in[8];
  const float* b2 = (const float*)d_in[9];
  const float* mw1 = (const float*)d_in[10];
  const float* mb1 = (const float*)d_in[11];
  const float* mw2 = (const float*)d_in[12];
  const float* mb2 = (const float*)d_in[13];
  float* out = (float*)d_out;

  char* ws = (char*)d_ws;
  size_t o = 0;
  auto alloc = [&](size_t bytes) {
    void* ptr = ws + o;
    o += (bytes + 255) & ~(size_t)255;
    return ptr;
  };
  int* counts = (int*)alloc((size_t)NN * 4);
  int* offsets = (int*)alloc((size_t)(NN + 1) * 4);
  int* cursor = (int*)alloc((size_t)NN * 4);
  int* bsums = (int*)alloc((size_t)NB * 4);
  int2* csr = (int2*)alloc((size_t)NE * 8);
  unsigned short* xb = (unsigned short*)alloc((size_t)NN * 128 * 2);
  unsigned short* w1t = (unsigned short*)alloc((size_t)256 * 128 * 2);
  unsigned short* w2t = (unsigned short*)alloc((size_t)64 * 256 * 2);
  unsigned short* pqt = (unsigned short*)alloc((size_t)128 * 64 * 2);
  unsigned short* h1b = (unsigned short*)alloc((size_t)NN * 256 * 2);  // reused h2b/pq
  float* a_s1 = (float*)alloc((size_t)NN * 4 * 4);
  float* a_d1 = (float*)alloc((size_t)NN * 4 * 4);
  unsigned short* x2b = (unsigned short*)alloc((size_t)NN * 256 * 2);
  unsigned short* yb = (unsigned short*)alloc((size_t)NN * 64 * 2);
  unsigned short* h2b = h1b;                  // NN*64
  unsigned short* pq = h1b + (size_t)NN * 64; // NN*128, [p|q]

  // CSR build + conversions
  hipMemsetAsync(counts, 0, (size_t)NN * 4, stream);
  prep_k<<<NHB + (NX4 + NW1 + NW2 + NPQ + 255) / 256, 256, 0, stream>>>(
      ei, counts, x, W1, W2, mw1, xb, w1t, w2t, pqt);
  scan_bsum_k<<<NB, 256, 0, stream>>>(counts, bsums);
  scan_final_k<<<NB, 256, 0, stream>>>(counts, bsums, offsets, cursor);
  scatter_k<<<(NE + 255) / 256, 256, 0, stream>>>(ei, cursor, csr);

  int gy = (NN + 63) / 64;
  // Layer 1: h1 = x @ W1 (MFMA, bf16) + fused dots; aggregate -> x2 (bf16)
  mgemm_k<1><<<dim3(4, gy), 256, 0, stream>>>(xb, 128, w1t, 128, h1b, 256,
                                              NN, 256, 128, as1w, ad1w, a_s1, a_d1, 4);
  gat_agg4_k<<<NN / 4, 256, 0, stream>>>(offsets, csr, h1b, a_s1, a_d1, b1, x2b);

  // Layer 2: h2 = x2 @ W2 (MFMA) + fused dots; aggregate -> y (bf16)
  mgemm_k<1><<<dim3(1, gy), 256, 0, stream>>>(x2b, 256, w2t, 256, h2b, 64,
                                              NN, 64, 256, as2w, ad2w, a_s1, a_d1, 1);
  gat_agg1_k<<<NN / 4, 256, 0, stream>>>(offsets, csr, h2b, a_s1, a_d1, b2, yb);

  // Edge MLP: pq = y @ [mw1[:64] | mw1[64:]]  (one MFMA GEMM, N=128)
  mgemm_k<0><<<dim3(2, gy), 256, 0, stream>>>(yb, 64, pqt, 64, pq, 128,
                                              NN, 128, 64, nullptr, nullptr,
                                              nullptr, nullptr, 0);

  // Final per-edge output (dst-grouped)
  edge_out_k<<<NN / 4, 256, 0, stream>>>(offsets, csr, pq, mb1, mw2, mb2, out);
}